// Round 2
// baseline (142.032 us; speedup 1.0000x reference)
//
#include <hip/hip_runtime.h>

#define N_FEAT 2048
#define ORDER 8
#define BATCH 8192
#define BLOCK 256
#define ROWS 4          // batch rows per block
#define NPAIR 28        // ORDER*(ORDER-1)/2

typedef float v4f __attribute__((ext_vector_type(4)));

__device__ __forceinline__ float dot4(v4f a, v4f b) {
    return a.x * b.x + a.y * b.y + a.z * b.z + a.w * b.w;
}

// ---- prep (1 block): normalize v -> vn, build compact-WY T (8x8) ----------
// H0*H1*...*H7 = I - V T V^T ; T_{k+1} = [[T_k, -2 T_k g],[0,2]], g_j = vj.vk
__global__ __launch_bounds__(BLOCK) void prep_kernel(
    const float* __restrict__ v, float* __restrict__ vn,
    float* __restrict__ Tm) {
    const int tid = threadIdx.x;
    const int lane = tid & 63, wid = tid >> 6;

    v4f a0[ORDER], a1[ORDER];
    #pragma unroll
    for (int i = 0; i < ORDER; ++i) {
        a0[i] = *(const v4f*)(v + (size_t)i * N_FEAT + tid * 4);
        a1[i] = *(const v4f*)(v + (size_t)i * N_FEAT + 1024 + tid * 4);
    }
    float ss[ORDER];
    #pragma unroll
    for (int i = 0; i < ORDER; ++i)
        ss[i] = dot4(a0[i], a0[i]) + dot4(a1[i], a1[i]);
    #pragma unroll
    for (int o = 32; o > 0; o >>= 1)
        #pragma unroll
        for (int i = 0; i < ORDER; ++i) ss[i] += __shfl_down(ss[i], o, 64);

    __shared__ float red[4][ORDER];
    __shared__ float gred[4][NPAIR];
    if (lane == 0) {
        #pragma unroll
        for (int i = 0; i < ORDER; ++i) red[wid][i] = ss[i];
    }
    __syncthreads();
    #pragma unroll
    for (int i = 0; i < ORDER; ++i) {
        const float inv = 1.0f / sqrtf(red[0][i] + red[1][i] + red[2][i] + red[3][i]);
        a0[i] *= inv; a1[i] *= inv;
        *(v4f*)(vn + (size_t)i * N_FEAT + tid * 4) = a0[i];
        *(v4f*)(vn + (size_t)i * N_FEAT + 1024 + tid * 4) = a1[i];
    }

    // pairwise dots of the normalized vectors
    float gp[NPAIR];
    {
        int idx = 0;
        #pragma unroll
        for (int j = 0; j < ORDER; ++j)
            #pragma unroll
            for (int k = j + 1; k < ORDER; ++k)
                gp[idx++] = dot4(a0[j], a0[k]) + dot4(a1[j], a1[k]);
    }
    #pragma unroll
    for (int o = 32; o > 0; o >>= 1)
        #pragma unroll
        for (int q = 0; q < NPAIR; ++q) gp[q] += __shfl_down(gp[q], o, 64);
    if (lane == 0) {
        #pragma unroll
        for (int q = 0; q < NPAIR; ++q) gred[wid][q] = gp[q];
    }
    __syncthreads();

    if (tid == 0) {
        float G[ORDER][ORDER];
        {
            int idx = 0;
            #pragma unroll
            for (int j = 0; j < ORDER; ++j)
                #pragma unroll
                for (int k = j + 1; k < ORDER; ++k) {
                    G[j][k] = gred[0][idx] + gred[1][idx] + gred[2][idx] + gred[3][idx];
                    ++idx;
                }
        }
        float T[ORDER][ORDER];
        #pragma unroll
        for (int j = 0; j < ORDER; ++j)
            #pragma unroll
            for (int k = 0; k < ORDER; ++k) T[j][k] = 0.0f;
        T[0][0] = 2.0f;
        #pragma unroll
        for (int k = 1; k < ORDER; ++k) {
            #pragma unroll
            for (int j = 0; j < k; ++j) {
                float s = 0.0f;
                #pragma unroll
                for (int m = j; m < k; ++m) s += T[j][m] * G[m][k];
                T[j][k] = -2.0f * s;
            }
            T[k][k] = 2.0f;
        }
        #pragma unroll
        for (int j = 0; j < ORDER; ++j)
            #pragma unroll
            for (int k = 0; k < ORDER; ++k)
                Tm[j * ORDER + k] = T[j][k];
    }
}

// ---- apply: y = (x - (x V) T V^T) * d + bias -------------------------------
// ONE reduction + ONE barrier per block (vs 8 serial chains before).
__global__ __launch_bounds__(BLOCK) void orth_apply_kernel(
    const float* __restrict__ x, const float* __restrict__ vn,
    const float* __restrict__ Tm, const float* __restrict__ d,
    const float* __restrict__ bias, float* __restrict__ y) {
    const int tid = threadIdx.x;
    const int lane = tid & 63, wid = tid >> 6;
    const size_t base = (size_t)blockIdx.x * ROWS * N_FEAT;
    const int c0 = tid * 4;
    const int c1 = 1024 + tid * 4;

    // x is read-once: nontemporal keeps vn/T/d/bias resident in L1/L2.
    v4f z0[ROWS], z1[ROWS];
    #pragma unroll
    for (int r = 0; r < ROWS; ++r) {
        z0[r] = __builtin_nontemporal_load((const v4f*)(x + base + (size_t)r * N_FEAT + c0));
        z1[r] = __builtin_nontemporal_load((const v4f*)(x + base + (size_t)r * N_FEAT + c1));
    }

    // Phase 1: all 8 projections p[r][i] = z_r . v_i  (independent -> full ILP)
    float p[ROWS][ORDER];
    #pragma unroll
    for (int i = 0; i < ORDER; ++i) {
        const v4f a0 = *(const v4f*)(vn + (size_t)i * N_FEAT + c0);
        const v4f a1 = *(const v4f*)(vn + (size_t)i * N_FEAT + c1);
        #pragma unroll
        for (int r = 0; r < ROWS; ++r)
            p[r][i] = dot4(z0[r], a0) + dot4(z1[r], a1);
    }

    // One butterfly over 32 independent partials (latencies pipeline).
    #pragma unroll
    for (int o = 32; o > 0; o >>= 1)
        #pragma unroll
        for (int r = 0; r < ROWS; ++r)
            #pragma unroll
            for (int i = 0; i < ORDER; ++i)
                p[r][i] += __shfl_down(p[r][i], o, 64);

    __shared__ float red[4][ROWS][ORDER];
    if (lane == 0) {
        #pragma unroll
        for (int r = 0; r < ROWS; ++r)
            #pragma unroll
            for (int i = 0; i < ORDER; ++i) red[wid][r][i] = p[r][i];
    }
    __syncthreads();   // the ONLY barrier in the kernel

    #pragma unroll
    for (int r = 0; r < ROWS; ++r)
        #pragma unroll
        for (int i = 0; i < ORDER; ++i)
            p[r][i] = red[0][r][i] + red[1][r][i] + red[2][r][i] + red[3][r][i];

    // c = p @ T  (T upper-triangular; wave-uniform -> scalar loads into SGPRs)
    float c[ROWS][ORDER];
    #pragma unroll
    for (int i = 0; i < ORDER; ++i)
        #pragma unroll
        for (int r = 0; r < ROWS; ++r) {
            float s = 0.0f;
            #pragma unroll
            for (int j = 0; j <= i; ++j) s += p[r][j] * Tm[j * ORDER + i];
            c[r][i] = s;
        }

    // Phase 2: z -= sum_i c_i * v_i. Reload vn through a laundered pointer so
    // the compiler re-reads from L1 instead of keeping 16 v4f live (+64 VGPR).
    const float* vnr;
    {
        unsigned long long pv = (unsigned long long)vn;
        asm volatile("" : "+s"(pv));
        vnr = (const float*)pv;
    }
    #pragma unroll
    for (int i = 0; i < ORDER; ++i) {
        const v4f a0 = *(const v4f*)(vnr + (size_t)i * N_FEAT + c0);
        const v4f a1 = *(const v4f*)(vnr + (size_t)i * N_FEAT + c1);
        #pragma unroll
        for (int r = 0; r < ROWS; ++r) {
            z0[r] -= c[r][i] * a0;
            z1[r] -= c[r][i] * a1;
        }
    }

    const v4f d0 = *(const v4f*)(d + c0);
    const v4f d1 = *(const v4f*)(d + c1);
    const v4f b0 = *(const v4f*)(bias + c0);
    const v4f b1 = *(const v4f*)(bias + c1);
    #pragma unroll
    for (int r = 0; r < ROWS; ++r) {
        v4f o0 = z0[r] * d0 + b0;
        v4f o1 = z1[r] * d1 + b1;
        __builtin_nontemporal_store(o0, (v4f*)(y + base + (size_t)r * N_FEAT + c0));
        __builtin_nontemporal_store(o1, (v4f*)(y + base + (size_t)r * N_FEAT + c1));
    }
}

extern "C" void kernel_launch(void* const* d_in, const int* in_sizes, int n_in,
                              void* d_out, int out_size, void* d_ws, size_t ws_size,
                              hipStream_t stream) {
    const float* x    = (const float*)d_in[0];  // [8192, 2048]
    const float* v    = (const float*)d_in[1];  // [8, 2048]
    const float* d    = (const float*)d_in[2];  // [2048]
    const float* bias = (const float*)d_in[3];  // [2048]
    float* y  = (float*)d_out;                  // [8192, 2048]
    float* vn = (float*)d_ws;                   // [8, 2048] normalized vectors
    float* Tm = vn + ORDER * N_FEAT;            // [8, 8] WY T-factor (64 KB + 256 B of ws)

    prep_kernel<<<1, BLOCK, 0, stream>>>(v, vn, Tm);
    orth_apply_kernel<<<BATCH / ROWS, BLOCK, 0, stream>>>(x, vn, Tm, d, bias, y);
}

// Round 3
// 134.079 us; speedup vs baseline: 1.0593x; 1.0593x over previous
//
#include <hip/hip_runtime.h>

#define N_FEAT 2048
#define ORDER 8
#define BATCH 8192
#define BLOCK 256
#define ROWS 4          // batch rows per block
#define NPAIR 28        // ORDER*(ORDER-1)/2

typedef float v4f __attribute__((ext_vector_type(4)));

__device__ __forceinline__ float dot4(v4f a, v4f b) {
    return a.x * b.x + a.y * b.y + a.z * b.z + a.w * b.w;
}

// launder a pointer so the compiler cannot CSE loads through it with
// earlier loads (forces a genuine reload, frees the old registers).
__device__ __forceinline__ const float* launder(const float* p) {
    unsigned long long v = (unsigned long long)p;
    asm volatile("" : "+s"(v));
    return (const float*)v;
}

// ---- prep (1 block): normalize v -> vn, build compact-WY T (8x8) ----------
// H0*H1*...*H7 = I - V T V^T ; T_{k+1} = [[T_k, -2 T_k g],[0,2]], g_j = vj.vk
__global__ __launch_bounds__(BLOCK) void prep_kernel(
    const float* __restrict__ v, float* __restrict__ vn,
    float* __restrict__ Tm) {
    const int tid = threadIdx.x;
    const int lane = tid & 63, wid = tid >> 6;

    v4f a0[ORDER], a1[ORDER];
    #pragma unroll
    for (int i = 0; i < ORDER; ++i) {
        a0[i] = *(const v4f*)(v + (size_t)i * N_FEAT + tid * 4);
        a1[i] = *(const v4f*)(v + (size_t)i * N_FEAT + 1024 + tid * 4);
    }
    float ss[ORDER];
    #pragma unroll
    for (int i = 0; i < ORDER; ++i)
        ss[i] = dot4(a0[i], a0[i]) + dot4(a1[i], a1[i]);
    #pragma unroll
    for (int o = 32; o > 0; o >>= 1)
        #pragma unroll
        for (int i = 0; i < ORDER; ++i) ss[i] += __shfl_down(ss[i], o, 64);

    __shared__ float red[4][ORDER];
    __shared__ float gred[4][NPAIR];
    if (lane == 0) {
        #pragma unroll
        for (int i = 0; i < ORDER; ++i) red[wid][i] = ss[i];
    }
    __syncthreads();
    #pragma unroll
    for (int i = 0; i < ORDER; ++i) {
        const float inv = 1.0f / sqrtf(red[0][i] + red[1][i] + red[2][i] + red[3][i]);
        a0[i] *= inv; a1[i] *= inv;
        *(v4f*)(vn + (size_t)i * N_FEAT + tid * 4) = a0[i];
        *(v4f*)(vn + (size_t)i * N_FEAT + 1024 + tid * 4) = a1[i];
    }

    float gp[NPAIR];
    {
        int idx = 0;
        #pragma unroll
        for (int j = 0; j < ORDER; ++j)
            #pragma unroll
            for (int k = j + 1; k < ORDER; ++k)
                gp[idx++] = dot4(a0[j], a0[k]) + dot4(a1[j], a1[k]);
    }
    #pragma unroll
    for (int o = 32; o > 0; o >>= 1)
        #pragma unroll
        for (int q = 0; q < NPAIR; ++q) gp[q] += __shfl_down(gp[q], o, 64);
    if (lane == 0) {
        #pragma unroll
        for (int q = 0; q < NPAIR; ++q) gred[wid][q] = gp[q];
    }
    __syncthreads();

    if (tid == 0) {
        float G[ORDER][ORDER];
        {
            int idx = 0;
            #pragma unroll
            for (int j = 0; j < ORDER; ++j)
                #pragma unroll
                for (int k = j + 1; k < ORDER; ++k) {
                    G[j][k] = gred[0][idx] + gred[1][idx] + gred[2][idx] + gred[3][idx];
                    ++idx;
                }
        }
        float T[ORDER][ORDER];
        #pragma unroll
        for (int j = 0; j < ORDER; ++j)
            #pragma unroll
            for (int k = 0; k < ORDER; ++k) T[j][k] = 0.0f;
        T[0][0] = 2.0f;
        #pragma unroll
        for (int k = 1; k < ORDER; ++k) {
            #pragma unroll
            for (int j = 0; j < k; ++j) {
                float s = 0.0f;
                #pragma unroll
                for (int m = j; m < k; ++m) s += T[j][m] * G[m][k];
                T[j][k] = -2.0f * s;
            }
            T[k][k] = 2.0f;
        }
        #pragma unroll
        for (int j = 0; j < ORDER; ++j)
            #pragma unroll
            for (int k = 0; k < ORDER; ++k)
                Tm[j * ORDER + k] = T[j][k];
    }
}

// ---- apply: y = (x - (x V) T V^T) * d + bias -------------------------------
// Two-pass over x (no persistent z): phase 1 computes p = x.V, packed-b128
// LDS combine (ONE barrier), c = p@T in-reg; phase 2 accumulates sum_i c_i v_i
// and re-reads x (L2/L3-hot, addresses independent of the reduction).
// __launch_bounds__(256,4): VGPR<=128 -> 8 blocks/CU, all 32 waves resident.
__global__ __launch_bounds__(BLOCK, 4) void orth_apply_kernel(
    const float* __restrict__ x, const float* __restrict__ vn,
    const float* __restrict__ Tm, const float* __restrict__ d,
    const float* __restrict__ bias, float* __restrict__ y) {
    const int tid = threadIdx.x;
    const int lane = tid & 63, wid = tid >> 6;
    const size_t base = (size_t)blockIdx.x * ROWS * N_FEAT;
    const int c0 = tid * 4;
    const int c1 = 1024 + tid * 4;

    // Phase 1: p[r][i] = x_r . v_i over this thread's 8 columns.
    // x loads CACHED (re-read in phase 2 must hit L2/L3).
    float p[ROWS][ORDER];
    {
        v4f x0[ROWS], x1[ROWS];
        #pragma unroll
        for (int r = 0; r < ROWS; ++r) {
            x0[r] = *(const v4f*)(x + base + (size_t)r * N_FEAT + c0);
            x1[r] = *(const v4f*)(x + base + (size_t)r * N_FEAT + c1);
        }
        #pragma unroll
        for (int i = 0; i < ORDER; ++i) {
            const v4f a0 = *(const v4f*)(vn + (size_t)i * N_FEAT + c0);
            const v4f a1 = *(const v4f*)(vn + (size_t)i * N_FEAT + c1);
            #pragma unroll
            for (int r = 0; r < ROWS; ++r)
                p[r][i] = dot4(x0[r], a0) + dot4(x1[r], a1);
        }
    }   // x0/x1 die here -> registers freed for phase 2

    // In-wave butterfly: lane 0 ends with the wave-partial for all 32 values.
    #pragma unroll
    for (int o = 32; o > 0; o >>= 1)
        #pragma unroll
        for (int r = 0; r < ROWS; ++r)
            #pragma unroll
            for (int i = 0; i < ORDER; ++i)
                p[r][i] += __shfl_down(p[r][i], o, 64);

    // Packed cross-wave combine: 8x ds_write_b128 (lane0) + 32x ds_read_b128
    // broadcast per thread — replaces the 128 scalar ds_read_b32 of v2.
    __shared__ v4f red[4][ROWS][2];
    if (lane == 0) {
        #pragma unroll
        for (int r = 0; r < ROWS; ++r) {
            v4f lo, hi;
            lo.x = p[r][0]; lo.y = p[r][1]; lo.z = p[r][2]; lo.w = p[r][3];
            hi.x = p[r][4]; hi.y = p[r][5]; hi.z = p[r][6]; hi.w = p[r][7];
            red[wid][r][0] = lo;
            red[wid][r][1] = hi;
        }
    }
    __syncthreads();   // the ONLY barrier

    v4f ps[ROWS][2];
    #pragma unroll
    for (int r = 0; r < ROWS; ++r) {
        ps[r][0] = (red[0][r][0] + red[1][r][0]) + (red[2][r][0] + red[3][r][0]);
        ps[r][1] = (red[0][r][1] + red[1][r][1]) + (red[2][r][1] + red[3][r][1]);
    }

    // c = p @ T (T upper-triangular, wave-uniform -> scalar loads)
    float c[ROWS][ORDER];
    #pragma unroll
    for (int i = 0; i < ORDER; ++i)
        #pragma unroll
        for (int r = 0; r < ROWS; ++r) {
            float s = 0.0f;
            #pragma unroll
            for (int j = 0; j <= i; ++j)
                s += ps[r][j >> 2][j & 3] * Tm[j * ORDER + i];
            c[r][i] = s;
        }

    // Phase 2: acc_r = sum_i c[r][i] * v_i (vn reloaded — laundered so the
    // compiler doesn't keep 16 v4f alive across the barrier).
    const float* vnr = launder(vn);
    v4f acc0[ROWS], acc1[ROWS];
    #pragma unroll
    for (int r = 0; r < ROWS; ++r) { acc0[r] = (v4f)0.0f; acc1[r] = (v4f)0.0f; }
    #pragma unroll
    for (int i = 0; i < ORDER; ++i) {
        const v4f a0 = *(const v4f*)(vnr + (size_t)i * N_FEAT + c0);
        const v4f a1 = *(const v4f*)(vnr + (size_t)i * N_FEAT + c1);
        #pragma unroll
        for (int r = 0; r < ROWS; ++r) {
            acc0[r] += c[r][i] * a0;
            acc1[r] += c[r][i] * a1;
        }
    }

    // Epilogue: re-read x (L2/L3-hot; nt = evict-first, it's the last use),
    // y = (x - acc) * d + bias, nontemporal store.
    const float* xr = launder(x);
    const v4f d0 = *(const v4f*)(d + c0);
    const v4f d1 = *(const v4f*)(d + c1);
    const v4f b0 = *(const v4f*)(bias + c0);
    const v4f b1 = *(const v4f*)(bias + c1);
    #pragma unroll
    for (int r = 0; r < ROWS; ++r) {
        const v4f xa = __builtin_nontemporal_load(
            (const v4f*)(xr + base + (size_t)r * N_FEAT + c0));
        const v4f xb = __builtin_nontemporal_load(
            (const v4f*)(xr + base + (size_t)r * N_FEAT + c1));
        v4f o0 = (xa - acc0[r]) * d0 + b0;
        v4f o1 = (xb - acc1[r]) * d1 + b1;
        __builtin_nontemporal_store(o0, (v4f*)(y + base + (size_t)r * N_FEAT + c0));
        __builtin_nontemporal_store(o1, (v4f*)(y + base + (size_t)r * N_FEAT + c1));
    }
}

extern "C" void kernel_launch(void* const* d_in, const int* in_sizes, int n_in,
                              void* d_out, int out_size, void* d_ws, size_t ws_size,
                              hipStream_t stream) {
    const float* x    = (const float*)d_in[0];  // [8192, 2048]
    const float* v    = (const float*)d_in[1];  // [8, 2048]
    const float* d    = (const float*)d_in[2];  // [2048]
    const float* bias = (const float*)d_in[3];  // [2048]
    float* y  = (float*)d_out;                  // [8192, 2048]
    float* vn = (float*)d_ws;                   // [8, 2048] normalized vectors
    float* Tm = vn + ORDER * N_FEAT;            // [8, 8] WY T-factor

    prep_kernel<<<1, BLOCK, 0, stream>>>(v, vn, Tm);
    orth_apply_kernel<<<BATCH / ROWS, BLOCK, 0, stream>>>(x, vn, Tm, d, bias, y);
}